// Round 7
// baseline (85.888 us; speedup 1.0000x reference)
//
#include <hip/hip_runtime.h>
#include <hip/hip_bf16.h>
#include <stdint.h>

#define BSZ 384
#define DD  256
#define NWAVES 6
#define NANCH 2                    // anchors per block
#define NBLK (BSZ / NANCH)         // 192 blocks
#define NEG_BIG -3.0e38f

// ---------------- threefry2x32, key = (0, 42) = jax.random.key(42) -----------
__device__ __forceinline__ void threefry_0_42(uint32_t c0, uint32_t c1,
                                              uint32_t& o0, uint32_t& o1) {
    const uint32_t k0 = 0u;
    const uint32_t k1 = 42u;
    const uint32_t k2 = 0u ^ 42u ^ 0x1BD11BDAu;
    uint32_t x0 = c0 + k0;
    uint32_t x1 = c1 + k1;
#define TF_RND(R) { x0 += x1; x1 = (x1 << (R)) | (x1 >> (32 - (R))); x1 ^= x0; }
    TF_RND(13) TF_RND(15) TF_RND(26) TF_RND(6)
    x0 += k1; x1 += k2 + 1u;
    TF_RND(17) TF_RND(29) TF_RND(16) TF_RND(24)
    x0 += k2; x1 += k0 + 2u;
    TF_RND(13) TF_RND(15) TF_RND(26) TF_RND(6)
    x0 += k0; x1 += k1 + 3u;
    TF_RND(17) TF_RND(29) TF_RND(16) TF_RND(24)
    x0 += k1; x1 += k2 + 4u;
    TF_RND(13) TF_RND(15) TF_RND(26) TF_RND(6)
    x0 += k2; x1 += k0 + 5u;
#undef TF_RND
    o0 = x0; o1 = x1;
}

// gumbel[idx] under jax_threefry_partitionable=True: cipher(0, idx), r0^r1.
// (Bit-exact vs reference: rounds 2-6 absmax 0.0.)
__device__ __forceinline__ float gumbel_at(uint32_t idx) {
    uint32_t r0, r1;
    threefry_0_42(0u, idx, r0, r1);
    uint32_t bits = r0 ^ r1;
    uint32_t mant = bits >> 9;
    float f = __uint_as_float(mant | 0x3F800000u) - 1.0f; // exact in [0,1)
    float u = (mant == 0u) ? 1.17549435e-38f : f;         // minval = f32 tiny
    return -logf(-logf(u));
}

// Kernel 1: 192 blocks x 384 threads, 2 anchors per block.
//   Phase 1: coalesced 8-lanes-per-row dist (validated r6), both anchors
//     share each loaded F row -> L2 traffic halved (74 MB).
//   Phase 2: barrier-free wave-per-pair mining (validated r4-r6).
//   Phase 3: partial (tot, cnt) -> per-block slot, PLAIN STORES.
//     ZERO global atomics: r3-r6's 384x3 same-line device-scope RMWs
//     (cross-XCD line ping-pong) were the hidden ~20 us tail.
__global__ __launch_bounds__(BSZ) void fused_kernel(const float* __restrict__ F,
                                                    const int* __restrict__ labels,
                                                    const int* __restrict__ epochp,
                                                    float* __restrict__ tot_slot,
                                                    unsigned int* __restrict__ cnt_slot) {
    __shared__ float    row[NANCH][BSZ];
    __shared__ float    nlog[NANCH][BSZ];
    __shared__ int      slab[BSZ];
    __shared__ int      plist[NANCH * BSZ];  // entry = (a<<16) | j
    __shared__ int      npos;
    __shared__ float    wtot[NWAVES];
    __shared__ unsigned wcnt[NWAVES];

    const int i0   = blockIdx.x * NANCH;     // anchors i0, i0+1
    const int tid  = threadIdx.x;
    const int wave = tid >> 6;
    const int lane = tid & 63;
    const int rl   = lane >> 3;   // local row within wave's 8-row group
    const int s    = lane & 7;    // sub-lane within row (8 lanes/row)

    slab[tid] = labels[tid];
    if (tid == 0) npos = 0;
    __syncthreads();

    const int lab0 = slab[i0];
    const int lab1 = slab[i0 + 1];
    if (tid > i0     && slab[tid] == lab0) plist[atomicAdd(&npos, 1)] = tid;            // a=0
    if (tid > i0 + 1 && slab[tid] == lab1) plist[atomicAdd(&npos, 1)] = (1 << 16) | tid; // a=1
    const int  epoch   = *epochp;
    const bool semisel = (epoch > 3);
    __syncthreads();

    const int np = npos;
    float    t_total = 0.0f;
    unsigned t_count = 0u;

    if (np > 0) {   // np is block-uniform -> barriers below are safe
        const float4* F4 = (const float4*)F;

        // anchor fragments in registers (lane covers float4s t*8+s)
        float4 f0[8], f1[8];
#pragma unroll
        for (int t = 0; t < 8; ++t) {
            f0[t] = F4[(i0    ) * (DD / 4) + t * 8 + s];
            f1[t] = F4[(i0 + 1) * (DD / 4) + t * 8 + s];
        }

        for (int c = 0; c < 8; ++c) {
            const int k = c * 48 + wave * 8 + rl;
            const float4* fk = F4 + (size_t)k * (DD / 4);
            float a00 = 0.f, a01 = 0.f, a02 = 0.f, a03 = 0.f;
            float a10 = 0.f, a11 = 0.f, a12 = 0.f, a13 = 0.f;
#pragma unroll
            for (int t = 0; t < 8; ++t) {
                float4 b = fk[t * 8 + s];           // 8 rows x 128 B = 8 lines/load
                float d0 = f0[t].x - b.x, d1 = f0[t].y - b.y;
                float d2 = f0[t].z - b.z, d3 = f0[t].w - b.w;
                a00 = fmaf(d0, d0, a00); a01 = fmaf(d1, d1, a01);
                a02 = fmaf(d2, d2, a02); a03 = fmaf(d3, d3, a03);
                float e0 = f1[t].x - b.x, e1 = f1[t].y - b.y;
                float e2 = f1[t].z - b.z, e3 = f1[t].w - b.w;
                a10 = fmaf(e0, e0, a10); a11 = fmaf(e1, e1, a11);
                a12 = fmaf(e2, e2, a12); a13 = fmaf(e3, e3, a13);
            }
            float p0 = (a00 + a01) + (a02 + a03);
            float p1 = (a10 + a11) + (a12 + a13);
            p0 += __shfl_down(p0, 4, 64); p1 += __shfl_down(p1, 4, 64);
            p0 += __shfl_down(p0, 2, 64); p1 += __shfl_down(p1, 2, 64);
            p0 += __shfl_down(p0, 1, 64); p1 += __shfl_down(p1, 1, 64);
            if (s == 0) {
                row[0][k] = sqrtf(fmaxf(p0, 1e-11f));
                row[1][k] = sqrtf(fmaxf(p1, 1e-11f));
            }
        }
        __syncthreads();
        nlog[0][tid] = semisel ? -logf(row[0][tid]) : 0.0f;
        nlog[1][tid] = semisel ? -logf(row[1][tid]) : 0.0f;
        __syncthreads();

        // wave w owns pairs p = w, w+6, ... — no barriers below
        for (int p = wave; p < np; p += NWAVES) {
            const int   pl    = plist[p];
            const int   a     = pl >> 16;           // wave-uniform
            const int   j     = pl & 0xFFFF;
            const int   lab_a = a ? lab1 : lab0;
            const float* rwa  = row[a];
            const float d_pos = rwa[j];
            const float hi    = d_pos + 0.2f;
            const uint32_t jb = (uint32_t)((i0 + a) * BSZ + j) * (uint32_t)BSZ;
            float v  = NEG_BIG;
            int   kk = 0;
#pragma unroll
            for (int c = 0; c < BSZ / 64; ++c) {
                const int   k   = c * 64 + lane;
                const float dkk = rwa[k];
                const bool cand = (slab[k] != lab_a) &&
                                  (!semisel || (dkk > d_pos && dkk < hi));
                if (__any(cand)) {          // whole-chunk skip when no candidates
                    if (cand) {
                        float val = nlog[a][k] + gumbel_at(jb + (uint32_t)k);
                        if (val > v) { v = val; kk = k; }  // strict > keeps first max
                    }
                }
            }
            // wave argmax (val desc, idx asc — matches jnp.argmax first-max)
#pragma unroll
            for (int off = 32; off; off >>= 1) {
                float ov = __shfl_down(v, off, 64);
                int   oi = __shfl_down(kk, off, 64);
                if (ov > v || (ov == v && oi < kk)) { v = ov; kk = oi; }
            }
            if (lane == 0 && v > -1.0e38f) {  // has_neg
                t_total += fmaxf(d_pos - rwa[kk] + 0.2f, 0.0f);
                t_count += 1u;
            }
        }
    }

    if (lane == 0) { wtot[wave] = t_total; wcnt[wave] = t_count; }
    __syncthreads();
    if (tid == 0) {
        float    tt = 0.0f;
        unsigned cc = 0u;
#pragma unroll
        for (int q = 0; q < NWAVES; ++q) { tt += wtot[q]; cc += wcnt[q]; }
        tot_slot[blockIdx.x] = tt;    // plain stores — no atomics, no done flag
        cnt_slot[blockIdx.x] = cc;    // (always written: no ws-zeroing needed)
    }
}

// Kernel 2: one wave reduces the 192 per-block slots and writes the mean.
__global__ __launch_bounds__(64) void reduce_kernel(const float* __restrict__ tot_slot,
                                                    const unsigned int* __restrict__ cnt_slot,
                                                    float* __restrict__ out) {
    const int lane = threadIdx.x;
    float    t = 0.0f;
    unsigned c = 0u;
#pragma unroll
    for (int q = 0; q < NBLK / 64; ++q) {   // 3 slots per lane
        t += tot_slot[q * 64 + lane];
        c += cnt_slot[q * 64 + lane];
    }
#pragma unroll
    for (int off = 32; off; off >>= 1) {
        t += __shfl_down(t, off, 64);
        c += __shfl_down(c, off, 64);
    }
    if (lane == 0) out[0] = (c > 0u) ? (t / (float)c) : 0.0f;
}

extern "C" void kernel_launch(void* const* d_in, const int* in_sizes, int n_in,
                              void* d_out, int out_size, void* d_ws, size_t ws_size,
                              hipStream_t stream) {
    const float* F      = (const float*)d_in[0];
    const int*   labels = (const int*)d_in[1];
    const int*   epoch  = (const int*)d_in[2];
    float*       out    = (float*)d_out;

    if (ws_size < 2 * NBLK * sizeof(float)) return;  // safety
    float*        tot_slot = (float*)d_ws;
    unsigned int* cnt_slot = (unsigned int*)d_ws + NBLK;

    fused_kernel<<<NBLK, BSZ, 0, stream>>>(F, labels, epoch, tot_slot, cnt_slot);
    reduce_kernel<<<1, 64, 0, stream>>>(tot_slot, cnt_slot, out);
}